// Round 1
// 204.779 us; speedup vs baseline: 1.0757x; 1.0757x over previous
//
#include <hip/hip_runtime.h>
#include <math.h>

#define NUM_EXPERTS 8
#define CAPACITY 320
#define NGROUP 8
#define NTOK 2048
#define HID 2048
#define NTOKENS (NGROUP * NTOK)  // 16384

typedef float vfloat4 __attribute__((ext_vector_type(4)));  // native vector:
// __builtin_nontemporal_load requires scalar/native-vector, not HIP_vector_type.

// Kernel A: router logits + softmax max + argmax.
// R8: W staged in LDS. R7's inner loop issued 8 W loads per 2 hs loads; those
// W reloads (536 MB of L1/L2 traffic for a 64 KB matrix) occupied the vmem
// queue slots that should be streaming hs, capping hs BW at ~1.7 TB/s.
// Now: one 64 KB LDS copy of W per block; the K-loop's only global traffic is
// the hs stream (134 MB total, roofline ~21 us at 6.3 TB/s).
//
// Block = 512 threads = 16 teams of 32 lanes, 2 tokens/team -> 32 tokens per
// block, grid 512. LDS 64 KB/block -> 2 blocks/CU (128 KB of 160 KB), i.e.
// 16 waves/CU — same occupancy as R7 despite the LDS.
// W reads from LDS: lane c reads float4 (e*512 + i*32 + c) -> 16 B/lane
// contiguous, and the two 32-lane teams of a wave read IDENTICAL addresses
// (broadcast) -> conflict-free.
//
// R3/R5/R6 spill lesson: NO staging arrays for hs, NO __launch_bounds__ —
// inline load->consume only. hs loads stay nontemporal (zero reuse).
//
// fp64 accumulation unchanged (proven numerics: assoc error ~1e-13 cannot
// flip argmax vs the ~exact value; reference fp32 error is the 0.0039 absmax).
__global__ void router_logits_kernel(
    const float* __restrict__ hs, const float* __restrict__ Wt,
    const float* __restrict__ bias,
    float* __restrict__ out_logits, float* __restrict__ out_pmax,
    int* __restrict__ ws_idx)
{
    __shared__ float Wlds[NUM_EXPERTS * HID];  // 64 KB, exactly the static cap

    const int tid  = threadIdx.x;   // 0..511
    const int c    = tid & 31;      // lane within 32-lane team
    const int team = tid >> 5;      // 0..15
    const int tokA = blockIdx.x * 32 + team * 2;
    const int tokB = tokA + 1;

    // Stage W -> LDS: 4096 float4 across 512 threads = 8 vector copies each.
    // All blocks read the same 64 KB (L2-resident); ds_write_b128 contiguous.
    {
        vfloat4*       dst = (vfloat4*)Wlds;
        const vfloat4* src = (const vfloat4*)Wt;
#pragma unroll
        for (int j = 0; j < 8; ++j)
            dst[j * 512 + tid] = src[j * 512 + tid];
    }
    __syncthreads();

    const vfloat4* hsA = (const vfloat4*)(hs + (size_t)tokA * HID);
    const vfloat4* hsB = (const vfloat4*)(hs + (size_t)tokB * HID);
    const vfloat4* Wv  = (const vfloat4*)Wlds;

    double accA[NUM_EXPERTS], accB[NUM_EXPERTS];
#pragma unroll
    for (int e = 0; e < NUM_EXPERTS; ++e) { accA[e] = 0.0; accB[e] = 0.0; }

#pragma unroll 4
    for (int i = 0; i < 16; ++i) {
        const int q = i * 32 + c;   // float4 index within a row (H/4 = 512)
        vfloat4 a = __builtin_nontemporal_load(&hsA[q]);
        vfloat4 b = __builtin_nontemporal_load(&hsB[q]);
        double ax = (double)a.x, ay = (double)a.y;
        double az = (double)a.z, aw = (double)a.w;
        double bx = (double)b.x, by = (double)b.y;
        double bz = (double)b.z, bw = (double)b.w;
#pragma unroll
        for (int e = 0; e < NUM_EXPERTS; ++e) {
            vfloat4 w = Wv[e * (HID / 4) + q];   // ds_read_b128, conflict-free
            double wx = (double)w.x, wy = (double)w.y;
            double wz = (double)w.z, ww = (double)w.w;
            accA[e] += ax * wx + ay * wy + az * wz + aw * ww;
            accB[e] += bx * wx + by * wy + bz * wz + bw * ww;
        }
    }

    // Butterfly over the 5 chunk bits (teams are aligned 32-lane groups).
#pragma unroll
    for (int m = 1; m < 32; m <<= 1) {
#pragma unroll
        for (int e = 0; e < NUM_EXPERTS; ++e) {
            accA[e] += __shfl_xor(accA[e], m, 64);
            accB[e] += __shfl_xor(accB[e], m, 64);
        }
    }

    if (c == 0) {
        auto emit = [&](const double* acc, int t) {
            float lf[NUM_EXPERTS];
#pragma unroll
            for (int e = 0; e < NUM_EXPERTS; ++e)
                lf[e] = (float)(acc[e] + (double)bias[e]);
            // first-occurrence argmax (matches jnp.argmax tie-break)
            float mx = lf[0];
            int idx = 0;
#pragma unroll
            for (int e = 1; e < NUM_EXPERTS; ++e)
                if (lf[e] > mx) { mx = lf[e]; idx = e; }
            float sum = 0.0f;
#pragma unroll
            for (int e = 0; e < NUM_EXPERTS; ++e)
                sum += expf(lf[e] - mx);
            float4* lp = (float4*)(out_logits + (size_t)t * NUM_EXPERTS);
            lp[0] = make_float4(lf[0], lf[1], lf[2], lf[3]);
            lp[1] = make_float4(lf[4], lf[5], lf[6], lf[7]);
            out_pmax[t] = 1.0f / sum;   // exp(mx-mx)/sum
            ws_idx[t] = idx;
        };
        emit(accA, tokA);
        emit(accB, tokB);
    }
}

// Kernel B: per-group inclusive cumsum of one-hot expert assignment + capacity
// mask. One block per group; thread tid owns tokens [tid*8, tid*8+8). Counts
// packed 16-bit x8 into 4 uint32 words; Hillis-Steele scan in LDS.
__global__ __launch_bounds__(256) void router_scan_kernel(
    const int* __restrict__ ws_idx, float* __restrict__ out_expert)
{
    __shared__ unsigned sb[4][256];
    const int g    = blockIdx.x;
    const int tid  = threadIdx.x;
    const int tok0 = g * NTOK + tid * 8;

    int idx[8];
#pragma unroll
    for (int j = 0; j < 8; ++j) idx[j] = ws_idx[tok0 + j];

    unsigned lc[4] = {0u, 0u, 0u, 0u};
#pragma unroll
    for (int j = 0; j < 8; ++j)
        lc[idx[j] >> 1] += 1u << ((idx[j] & 1) * 16);

#pragma unroll
    for (int w = 0; w < 4; ++w) sb[w][tid] = lc[w];
    __syncthreads();

    for (int off = 1; off < 256; off <<= 1) {
        unsigned v[4];
#pragma unroll
        for (int w = 0; w < 4; ++w)
            v[w] = (tid >= off) ? sb[w][tid - off] : 0u;
        __syncthreads();
#pragma unroll
        for (int w = 0; w < 4; ++w) sb[w][tid] += v[w];
        __syncthreads();
    }

    // exclusive prefix counts per expert (inclusive - local)
    unsigned run[NUM_EXPERTS];
#pragma unroll
    for (int e = 0; e < NUM_EXPERTS; ++e)
        run[e] = ((sb[e >> 1][tid] - lc[e >> 1]) >> ((e & 1) * 16)) & 0xFFFFu;

#pragma unroll
    for (int j = 0; j < 8; ++j) {
        const int e = idx[j];
        run[e] += 1u;  // inclusive token_priority for this token's expert
        const float keep = (run[e] <= CAPACITY) ? 1.0f : 0.0f;
        float vv[NUM_EXPERTS];
#pragma unroll
        for (int k = 0; k < NUM_EXPERTS; ++k)
            vv[k] = (k == e) ? keep : 0.0f;
        float4* op = (float4*)(out_expert + (size_t)(tok0 + j) * NUM_EXPERTS);
        op[0] = make_float4(vv[0], vv[1], vv[2], vv[3]);
        op[1] = make_float4(vv[4], vv[5], vv[6], vv[7]);
    }
}

extern "C" void kernel_launch(void* const* d_in, const int* in_sizes, int n_in,
                              void* d_out, int out_size, void* d_ws, size_t ws_size,
                              hipStream_t stream) {
    const float* hs = (const float*)d_in[0];
    const float* W  = (const float*)d_in[1];
    const float* b  = (const float*)d_in[2];

    float* out        = (float*)d_out;
    float* out_expert = out;                                      // [G,T,E] one-hot (as float)
    float* out_pmax   = out + (size_t)NTOKENS * NUM_EXPERTS;      // [G,T,1]
    float* out_logits = out_pmax + NTOKENS;                       // [G,T,E]
    int*   ws_idx     = (int*)d_ws;                               // [G*T] argmax expert ids

    router_logits_kernel<<<NTOKENS / 32, 512, 0, stream>>>(hs, W, b,
                                                           out_logits, out_pmax, ws_idx);
    router_scan_kernel<<<NGROUP, 256, 0, stream>>>(ws_idx, out_expert);
}

// Round 2
// 203.776 us; speedup vs baseline: 1.0809x; 1.0049x over previous
//
#include <hip/hip_runtime.h>
#include <math.h>

#define NUM_EXPERTS 8
#define CAPACITY 320
#define NGROUP 8
#define NTOK 2048
#define HID 2048
#define NTOKENS (NGROUP * NTOK)  // 16384

typedef float vfloat4 __attribute__((ext_vector_type(4)));  // native vector:
// __builtin_nontemporal_load requires scalar/native-vector, not HIP_vector_type.

// Kernel A: router logits + softmax max + argmax.
// R9: fp32 accumulation. R6/R7/R8 all plateaued at ~2 TB/s hs BW despite three
// different W paths (global / L1 / LDS) — the shared tax was fp64: 64
// v_fma_f64 (4 cyc) + 40 v_cvt_f64_f32 per wave-iter ≈ 420 VALU cyc per 2 KB
// of hs, plus a 128+ VGPR fp64 footprint that blocks cross-body load hoisting.
// fp32 cuts VALU/iter ~3x and halves the register footprint.
//
// Numerics: per-lane sum is only 64 products (partials <= 0.2), then an
// exact-ordering butterfly -> fp32 error ~5e-7. The reference's own logits
// carry ~4e-3 error (absmax 0.0039 = 2^-8 is reference-side), and fp64-exact
// matched its argmax on every token, so fp32 (diff vs fp64 < 1e-6) matches too
// unless a token's top-2 gap is <1e-6 — which would already have been a
// coin-flip for the reference itself.
//
// Structure unchanged from R8 (clean A/B on the accumulation dtype):
// W staged once per block into 64 KB LDS; block = 512 threads = 16 teams of
// 32 lanes, 2 tokens/team -> 32 tokens/block, grid 512; 2 blocks/CU
// (128 KB LDS), 16 waves/CU. W LDS reads are 16 B/lane contiguous and the two
// 32-lane teams of a wave read identical addresses (broadcast, conflict-free).
//
// R3/R5/R6 spill lesson: NO staging arrays for hs, NO __launch_bounds__ —
// inline load->consume only. hs loads stay nontemporal (zero reuse).
__global__ void router_logits_kernel(
    const float* __restrict__ hs, const float* __restrict__ Wt,
    const float* __restrict__ bias,
    float* __restrict__ out_logits, float* __restrict__ out_pmax,
    int* __restrict__ ws_idx)
{
    __shared__ float Wlds[NUM_EXPERTS * HID];  // 64 KB, exactly the static cap

    const int tid  = threadIdx.x;   // 0..511
    const int c    = tid & 31;      // lane within 32-lane team
    const int team = tid >> 5;      // 0..15
    const int tokA = blockIdx.x * 32 + team * 2;
    const int tokB = tokA + 1;

    // Stage W -> LDS: 4096 float4 across 512 threads = 8 vector copies each.
    // All blocks read the same 64 KB (L2-resident); ds_write_b128 contiguous.
    {
        vfloat4*       dst = (vfloat4*)Wlds;
        const vfloat4* src = (const vfloat4*)Wt;
#pragma unroll
        for (int j = 0; j < 8; ++j)
            dst[j * 512 + tid] = src[j * 512 + tid];
    }
    __syncthreads();

    const vfloat4* hsA = (const vfloat4*)(hs + (size_t)tokA * HID);
    const vfloat4* hsB = (const vfloat4*)(hs + (size_t)tokB * HID);
    const vfloat4* Wv  = (const vfloat4*)Wlds;

    float accA[NUM_EXPERTS], accB[NUM_EXPERTS];
#pragma unroll
    for (int e = 0; e < NUM_EXPERTS; ++e) { accA[e] = 0.0f; accB[e] = 0.0f; }

#pragma unroll 4
    for (int i = 0; i < 16; ++i) {
        const int q = i * 32 + c;   // float4 index within a row (H/4 = 512)
        vfloat4 a = __builtin_nontemporal_load(&hsA[q]);
        vfloat4 b = __builtin_nontemporal_load(&hsB[q]);
#pragma unroll
        for (int e = 0; e < NUM_EXPERTS; ++e) {
            vfloat4 w = Wv[e * (HID / 4) + q];   // ds_read_b128, conflict-free
            accA[e] += a.x * w.x + a.y * w.y + a.z * w.z + a.w * w.w;
            accB[e] += b.x * w.x + b.y * w.y + b.z * w.z + b.w * w.w;
        }
    }

    // Butterfly over the 5 chunk bits (teams are aligned 32-lane groups).
#pragma unroll
    for (int m = 1; m < 32; m <<= 1) {
#pragma unroll
        for (int e = 0; e < NUM_EXPERTS; ++e) {
            accA[e] += __shfl_xor(accA[e], m, 64);
            accB[e] += __shfl_xor(accB[e], m, 64);
        }
    }

    if (c == 0) {
        auto emit = [&](const float* acc, int t) {
            float lf[NUM_EXPERTS];
#pragma unroll
            for (int e = 0; e < NUM_EXPERTS; ++e)
                lf[e] = acc[e] + bias[e];
            // first-occurrence argmax (matches jnp.argmax tie-break)
            float mx = lf[0];
            int idx = 0;
#pragma unroll
            for (int e = 1; e < NUM_EXPERTS; ++e)
                if (lf[e] > mx) { mx = lf[e]; idx = e; }
            float sum = 0.0f;
#pragma unroll
            for (int e = 0; e < NUM_EXPERTS; ++e)
                sum += expf(lf[e] - mx);
            float4* lp = (float4*)(out_logits + (size_t)t * NUM_EXPERTS);
            lp[0] = make_float4(lf[0], lf[1], lf[2], lf[3]);
            lp[1] = make_float4(lf[4], lf[5], lf[6], lf[7]);
            out_pmax[t] = 1.0f / sum;   // exp(mx-mx)/sum
            ws_idx[t] = idx;
        };
        emit(accA, tokA);
        emit(accB, tokB);
    }
}

// Kernel B: per-group inclusive cumsum of one-hot expert assignment + capacity
// mask. One block per group; thread tid owns tokens [tid*8, tid*8+8). Counts
// packed 16-bit x8 into 4 uint32 words; Hillis-Steele scan in LDS.
__global__ __launch_bounds__(256) void router_scan_kernel(
    const int* __restrict__ ws_idx, float* __restrict__ out_expert)
{
    __shared__ unsigned sb[4][256];
    const int g    = blockIdx.x;
    const int tid  = threadIdx.x;
    const int tok0 = g * NTOK + tid * 8;

    int idx[8];
#pragma unroll
    for (int j = 0; j < 8; ++j) idx[j] = ws_idx[tok0 + j];

    unsigned lc[4] = {0u, 0u, 0u, 0u};
#pragma unroll
    for (int j = 0; j < 8; ++j)
        lc[idx[j] >> 1] += 1u << ((idx[j] & 1) * 16);

#pragma unroll
    for (int w = 0; w < 4; ++w) sb[w][tid] = lc[w];
    __syncthreads();

    for (int off = 1; off < 256; off <<= 1) {
        unsigned v[4];
#pragma unroll
        for (int w = 0; w < 4; ++w)
            v[w] = (tid >= off) ? sb[w][tid - off] : 0u;
        __syncthreads();
#pragma unroll
        for (int w = 0; w < 4; ++w) sb[w][tid] += v[w];
        __syncthreads();
    }

    // exclusive prefix counts per expert (inclusive - local)
    unsigned run[NUM_EXPERTS];
#pragma unroll
    for (int e = 0; e < NUM_EXPERTS; ++e)
        run[e] = ((sb[e >> 1][tid] - lc[e >> 1]) >> ((e & 1) * 16)) & 0xFFFFu;

#pragma unroll
    for (int j = 0; j < 8; ++j) {
        const int e = idx[j];
        run[e] += 1u;  // inclusive token_priority for this token's expert
        const float keep = (run[e] <= CAPACITY) ? 1.0f : 0.0f;
        float vv[NUM_EXPERTS];
#pragma unroll
        for (int k = 0; k < NUM_EXPERTS; ++k)
            vv[k] = (k == e) ? keep : 0.0f;
        float4* op = (float4*)(out_expert + (size_t)(tok0 + j) * NUM_EXPERTS);
        op[0] = make_float4(vv[0], vv[1], vv[2], vv[3]);
        op[1] = make_float4(vv[4], vv[5], vv[6], vv[7]);
    }
}

extern "C" void kernel_launch(void* const* d_in, const int* in_sizes, int n_in,
                              void* d_out, int out_size, void* d_ws, size_t ws_size,
                              hipStream_t stream) {
    const float* hs = (const float*)d_in[0];
    const float* W  = (const float*)d_in[1];
    const float* b  = (const float*)d_in[2];

    float* out        = (float*)d_out;
    float* out_expert = out;                                      // [G,T,E] one-hot (as float)
    float* out_pmax   = out + (size_t)NTOKENS * NUM_EXPERTS;      // [G,T,1]
    float* out_logits = out_pmax + NTOKENS;                       // [G,T,E]
    int*   ws_idx     = (int*)d_ws;                               // [G*T] argmax expert ids

    router_logits_kernel<<<NTOKENS / 32, 512, 0, stream>>>(hs, W, b,
                                                           out_logits, out_pmax, ws_idx);
    router_scan_kernel<<<NGROUP, 256, 0, stream>>>(ws_idx, out_expert);
}

// Round 3
// 192.588 us; speedup vs baseline: 1.1437x; 1.0581x over previous
//
#include <hip/hip_runtime.h>
#include <math.h>

#define NUM_EXPERTS 8
#define CAPACITY 320
#define NGROUP 8
#define NTOK 2048
#define HID 2048
#define NTOKENS (NGROUP * NTOK)  // 16384

typedef float vfloat4 __attribute__((ext_vector_type(4)));  // native vector:
// __builtin_nontemporal_load requires scalar/native-vector, not HIP_vector_type.

// Kernel A: router logits + softmax max + argmax.
// R10: attack memory-level parallelism, not ALU. R9 (fp64->fp32, ~3x VALU cut)
// was a NULL -> A is latency-bound: per unroll-4 body the wave issued its 8 hs
// loads at the top, then sat through 256 FMAs with ZERO loads in flight.
// Avg in-flight/CU ~5 KB vs ~12 KB (BW x 900cy latency) needed to saturate.
// Two fixes:
//   1. Explicit depth-1 prefetch with NAMED SCALARS (an/bn): iteration i+1's
//      hs loads are issued before iteration i's 64 FMAs. (R3/R5 spills came
//      from fp64 + runtime-indexed arrays — rule #20; named fp32 scalars are
//      +8 VGPR only.)
//   2. Block = 1024 threads (16 waves), grid 256, still 2 blocks/CU by LDS
//      (128 KB) -> 32 waves/CU (was 16). fp32 keeps VGPR low enough.
// W stays in 64 KB LDS (R8 win, -15 us): 16 B/lane contiguous, both 32-lane
// teams of a wave read identical addresses (broadcast, conflict-free).
// fp32 accumulation (R9, verified passing: absmax 0.0039 is reference-side).
__global__ void router_logits_kernel(
    const float* __restrict__ hs, const float* __restrict__ Wt,
    const float* __restrict__ bias,
    float* __restrict__ out_logits, float* __restrict__ out_pmax,
    int* __restrict__ ws_idx)
{
    __shared__ float Wlds[NUM_EXPERTS * HID];  // 64 KB, exactly the static cap

    const int tid  = threadIdx.x;   // 0..1023
    const int c    = tid & 31;      // lane within 32-lane team
    const int team = tid >> 5;      // 0..31
    const int tokA = blockIdx.x * 64 + team * 2;
    const int tokB = tokA + 1;

    // Stage W -> LDS: 4096 float4 across 1024 threads = 4 vector copies each.
    // All blocks read the same 64 KB (L2-resident); ds_write_b128 contiguous.
    {
        vfloat4*       dst = (vfloat4*)Wlds;
        const vfloat4* src = (const vfloat4*)Wt;
#pragma unroll
        for (int j = 0; j < 4; ++j)
            dst[j * 1024 + tid] = src[j * 1024 + tid];
    }
    __syncthreads();

    const vfloat4* hsA = (const vfloat4*)(hs + (size_t)tokA * HID);
    const vfloat4* hsB = (const vfloat4*)(hs + (size_t)tokB * HID);
    const vfloat4* Wv  = (const vfloat4*)Wlds;

    float accA[NUM_EXPERTS], accB[NUM_EXPERTS];
#pragma unroll
    for (int e = 0; e < NUM_EXPERTS; ++e) { accA[e] = 0.0f; accB[e] = 0.0f; }

    int q = c;                                  // float4 index in row (H/4=512)
    vfloat4 a = __builtin_nontemporal_load(&hsA[q]);
    vfloat4 b = __builtin_nontemporal_load(&hsB[q]);

#pragma unroll 2
    for (int i = 0; i < 15; ++i) {
        // prefetch next chunk BEFORE consuming current (keeps 2 loads/lane
        // in flight through the FMA stretch)
        vfloat4 an = __builtin_nontemporal_load(&hsA[q + 32]);
        vfloat4 bn = __builtin_nontemporal_load(&hsB[q + 32]);
#pragma unroll
        for (int e = 0; e < NUM_EXPERTS; ++e) {
            vfloat4 w = Wv[e * (HID / 4) + q];   // ds_read_b128, conflict-free
            accA[e] += a.x * w.x + a.y * w.y + a.z * w.z + a.w * w.w;
            accB[e] += b.x * w.x + b.y * w.y + b.z * w.z + b.w * w.w;
        }
        a = an; b = bn; q += 32;
    }
    // final chunk (no prefetch)
#pragma unroll
    for (int e = 0; e < NUM_EXPERTS; ++e) {
        vfloat4 w = Wv[e * (HID / 4) + q];
        accA[e] += a.x * w.x + a.y * w.y + a.z * w.z + a.w * w.w;
        accB[e] += b.x * w.x + b.y * w.y + b.z * w.z + b.w * w.w;
    }

    // Butterfly over the 5 chunk bits (teams are aligned 32-lane groups).
#pragma unroll
    for (int m = 1; m < 32; m <<= 1) {
#pragma unroll
        for (int e = 0; e < NUM_EXPERTS; ++e) {
            accA[e] += __shfl_xor(accA[e], m, 64);
            accB[e] += __shfl_xor(accB[e], m, 64);
        }
    }

    if (c == 0) {
        auto emit = [&](const float* acc, int t) {
            float lf[NUM_EXPERTS];
#pragma unroll
            for (int e = 0; e < NUM_EXPERTS; ++e)
                lf[e] = acc[e] + bias[e];
            // first-occurrence argmax (matches jnp.argmax tie-break)
            float mx = lf[0];
            int idx = 0;
#pragma unroll
            for (int e = 1; e < NUM_EXPERTS; ++e)
                if (lf[e] > mx) { mx = lf[e]; idx = e; }
            float sum = 0.0f;
#pragma unroll
            for (int e = 0; e < NUM_EXPERTS; ++e)
                sum += expf(lf[e] - mx);
            float4* lp = (float4*)(out_logits + (size_t)t * NUM_EXPERTS);
            lp[0] = make_float4(lf[0], lf[1], lf[2], lf[3]);
            lp[1] = make_float4(lf[4], lf[5], lf[6], lf[7]);
            out_pmax[t] = 1.0f / sum;   // exp(mx-mx)/sum
            ws_idx[t] = idx;
        };
        emit(accA, tokA);
        emit(accB, tokB);
    }
}

// Kernel B: per-group inclusive cumsum of one-hot expert assignment + capacity
// mask. One block per group; thread tid owns tokens [tid*8, tid*8+8). Counts
// packed 16-bit x8 into 4 uint32 words; Hillis-Steele scan in LDS.
__global__ __launch_bounds__(256) void router_scan_kernel(
    const int* __restrict__ ws_idx, float* __restrict__ out_expert)
{
    __shared__ unsigned sb[4][256];
    const int g    = blockIdx.x;
    const int tid  = threadIdx.x;
    const int tok0 = g * NTOK + tid * 8;

    int idx[8];
#pragma unroll
    for (int j = 0; j < 8; ++j) idx[j] = ws_idx[tok0 + j];

    unsigned lc[4] = {0u, 0u, 0u, 0u};
#pragma unroll
    for (int j = 0; j < 8; ++j)
        lc[idx[j] >> 1] += 1u << ((idx[j] & 1) * 16);

#pragma unroll
    for (int w = 0; w < 4; ++w) sb[w][tid] = lc[w];
    __syncthreads();

    for (int off = 1; off < 256; off <<= 1) {
        unsigned v[4];
#pragma unroll
        for (int w = 0; w < 4; ++w)
            v[w] = (tid >= off) ? sb[w][tid - off] : 0u;
        __syncthreads();
#pragma unroll
        for (int w = 0; w < 4; ++w) sb[w][tid] += v[w];
        __syncthreads();
    }

    // exclusive prefix counts per expert (inclusive - local)
    unsigned run[NUM_EXPERTS];
#pragma unroll
    for (int e = 0; e < NUM_EXPERTS; ++e)
        run[e] = ((sb[e >> 1][tid] - lc[e >> 1]) >> ((e & 1) * 16)) & 0xFFFFu;

#pragma unroll
    for (int j = 0; j < 8; ++j) {
        const int e = idx[j];
        run[e] += 1u;  // inclusive token_priority for this token's expert
        const float keep = (run[e] <= CAPACITY) ? 1.0f : 0.0f;
        float vv[NUM_EXPERTS];
#pragma unroll
        for (int k = 0; k < NUM_EXPERTS; ++k)
            vv[k] = (k == e) ? keep : 0.0f;
        float4* op = (float4*)(out_expert + (size_t)(tok0 + j) * NUM_EXPERTS);
        op[0] = make_float4(vv[0], vv[1], vv[2], vv[3]);
        op[1] = make_float4(vv[4], vv[5], vv[6], vv[7]);
    }
}

extern "C" void kernel_launch(void* const* d_in, const int* in_sizes, int n_in,
                              void* d_out, int out_size, void* d_ws, size_t ws_size,
                              hipStream_t stream) {
    const float* hs = (const float*)d_in[0];
    const float* W  = (const float*)d_in[1];
    const float* b  = (const float*)d_in[2];

    float* out        = (float*)d_out;
    float* out_expert = out;                                      // [G,T,E] one-hot (as float)
    float* out_pmax   = out + (size_t)NTOKENS * NUM_EXPERTS;      // [G,T,1]
    float* out_logits = out_pmax + NTOKENS;                       // [G,T,E]
    int*   ws_idx     = (int*)d_ws;                               // [G*T] argmax expert ids

    router_logits_kernel<<<NTOKENS / 64, 1024, 0, stream>>>(hs, W, b,
                                                            out_logits, out_pmax, ws_idx);
    router_scan_kernel<<<NGROUP, 256, 0, stream>>>(ws_idx, out_expert);
}

// Round 4
// 191.138 us; speedup vs baseline: 1.1524x; 1.0076x over previous
//
#include <hip/hip_runtime.h>
#include <math.h>

#define NUM_EXPERTS 8
#define CAPACITY 320
#define NGROUP 8
#define NTOK 2048
#define HID 2048
#define NTOKENS (NGROUP * NTOK)  // 16384

typedef float vfloat4 __attribute__((ext_vector_type(4)));  // native vector:
// __builtin_nontemporal_load requires scalar/native-vector, not HIP_vector_type.

// Kernel A: router logits + softmax max + argmax.
// R11: depth-2 hs prefetch. R10 (depth-1 + bigger blocks) matched prediction
// (-11 us) confirming A is hs-latency-bound, now ~26 us vs the 21.3 us stream
// floor (134 MB @ 6.3 TB/s). Issue->use distance at depth-1 is ~250 cyc of
// FMA/ds_read work < ~900 cyc HBM latency -> waves still micro-stall each
// iteration. Depth-2 (named rotation a0/a1/an, no runtime-indexed arrays —
// rule #20) doubles the distance (~500 cyc) and in-flight bytes (64 B/lane),
// +16 VGPR.
// Secondary pipes stay hidden: LDS ~6.8 us/CU, VALU ~3.4 us < 21 us stream.
// W in 64 KB LDS (R8): 16 B/lane contiguous, the wave's two 32-lane teams
// read identical addresses (broadcast, conflict-free). fp32 acc (R9, passes;
// absmax 0.0039 is reference-side fp32 error, unchanged across fp64/fp32).
__global__ void router_logits_kernel(
    const float* __restrict__ hs, const float* __restrict__ Wt,
    const float* __restrict__ bias,
    float* __restrict__ out_logits, float* __restrict__ out_pmax,
    int* __restrict__ ws_idx)
{
    __shared__ float Wlds[NUM_EXPERTS * HID];  // 64 KB, exactly the static cap

    const int tid  = threadIdx.x;   // 0..1023
    const int c    = tid & 31;      // lane within 32-lane team
    const int team = tid >> 5;      // 0..31
    const int tokA = blockIdx.x * 64 + team * 2;
    const int tokB = tokA + 1;

    // Stage W -> LDS: 4096 float4 across 1024 threads = 4 vector copies each.
    // All blocks read the same 64 KB (L2-resident); ds_write_b128 contiguous.
    {
        vfloat4*       dst = (vfloat4*)Wlds;
        const vfloat4* src = (const vfloat4*)Wt;
#pragma unroll
        for (int j = 0; j < 4; ++j)
            dst[j * 1024 + tid] = src[j * 1024 + tid];
    }
    __syncthreads();

    const vfloat4* hsA = (const vfloat4*)(hs + (size_t)tokA * HID);
    const vfloat4* hsB = (const vfloat4*)(hs + (size_t)tokB * HID);
    const vfloat4* Wv  = (const vfloat4*)Wlds;

    float accA[NUM_EXPERTS], accB[NUM_EXPERTS];
#pragma unroll
    for (int e = 0; e < NUM_EXPERTS; ++e) { accA[e] = 0.0f; accB[e] = 0.0f; }

    // depth-2 software pipeline, named-register rotation
    vfloat4 a0 = __builtin_nontemporal_load(&hsA[c]);
    vfloat4 b0 = __builtin_nontemporal_load(&hsB[c]);
    vfloat4 a1 = __builtin_nontemporal_load(&hsA[c + 32]);
    vfloat4 b1 = __builtin_nontemporal_load(&hsB[c + 32]);

    int q = c;                                  // float4 index in row (H/4=512)
#pragma unroll 2
    for (int i = 0; i < 14; ++i) {
        vfloat4 an = __builtin_nontemporal_load(&hsA[q + 64]);
        vfloat4 bn = __builtin_nontemporal_load(&hsB[q + 64]);
#pragma unroll
        for (int e = 0; e < NUM_EXPERTS; ++e) {
            vfloat4 w = Wv[e * (HID / 4) + q];   // ds_read_b128, conflict-free
            accA[e] += a0.x * w.x + a0.y * w.y + a0.z * w.z + a0.w * w.w;
            accB[e] += b0.x * w.x + b0.y * w.y + b0.z * w.z + b0.w * w.w;
        }
        a0 = a1; b0 = b1; a1 = an; b1 = bn; q += 32;
    }
    // drain: two remaining chunks (q and q+32), no prefetch
#pragma unroll
    for (int e = 0; e < NUM_EXPERTS; ++e) {
        vfloat4 w = Wv[e * (HID / 4) + q];
        accA[e] += a0.x * w.x + a0.y * w.y + a0.z * w.z + a0.w * w.w;
        accB[e] += b0.x * w.x + b0.y * w.y + b0.z * w.z + b0.w * w.w;
    }
#pragma unroll
    for (int e = 0; e < NUM_EXPERTS; ++e) {
        vfloat4 w = Wv[e * (HID / 4) + q + 32];
        accA[e] += a1.x * w.x + a1.y * w.y + a1.z * w.z + a1.w * w.w;
        accB[e] += b1.x * w.x + b1.y * w.y + b1.z * w.z + b1.w * w.w;
    }

    // Butterfly over the 5 chunk bits (teams are aligned 32-lane groups).
#pragma unroll
    for (int m = 1; m < 32; m <<= 1) {
#pragma unroll
        for (int e = 0; e < NUM_EXPERTS; ++e) {
            accA[e] += __shfl_xor(accA[e], m, 64);
            accB[e] += __shfl_xor(accB[e], m, 64);
        }
    }

    if (c == 0) {
        auto emit = [&](const float* acc, int t) {
            float lf[NUM_EXPERTS];
#pragma unroll
            for (int e = 0; e < NUM_EXPERTS; ++e)
                lf[e] = acc[e] + bias[e];
            // first-occurrence argmax (matches jnp.argmax tie-break)
            float mx = lf[0];
            int idx = 0;
#pragma unroll
            for (int e = 1; e < NUM_EXPERTS; ++e)
                if (lf[e] > mx) { mx = lf[e]; idx = e; }
            float sum = 0.0f;
#pragma unroll
            for (int e = 0; e < NUM_EXPERTS; ++e)
                sum += expf(lf[e] - mx);
            float4* lp = (float4*)(out_logits + (size_t)t * NUM_EXPERTS);
            lp[0] = make_float4(lf[0], lf[1], lf[2], lf[3]);
            lp[1] = make_float4(lf[4], lf[5], lf[6], lf[7]);
            out_pmax[t] = 1.0f / sum;   // exp(mx-mx)/sum
            ws_idx[t] = idx;
        };
        emit(accA, tokA);
        emit(accB, tokB);
    }
}

// Kernel B: per-group inclusive cumsum of one-hot expert assignment + capacity
// mask. One block per group; thread tid owns tokens [tid*8, tid*8+8). Counts
// packed 16-bit x8 into 4 uint32 words; Hillis-Steele scan in LDS.
__global__ __launch_bounds__(256) void router_scan_kernel(
    const int* __restrict__ ws_idx, float* __restrict__ out_expert)
{
    __shared__ unsigned sb[4][256];
    const int g    = blockIdx.x;
    const int tid  = threadIdx.x;
    const int tok0 = g * NTOK + tid * 8;

    int idx[8];
#pragma unroll
    for (int j = 0; j < 8; ++j) idx[j] = ws_idx[tok0 + j];

    unsigned lc[4] = {0u, 0u, 0u, 0u};
#pragma unroll
    for (int j = 0; j < 8; ++j)
        lc[idx[j] >> 1] += 1u << ((idx[j] & 1) * 16);

#pragma unroll
    for (int w = 0; w < 4; ++w) sb[w][tid] = lc[w];
    __syncthreads();

    for (int off = 1; off < 256; off <<= 1) {
        unsigned v[4];
#pragma unroll
        for (int w = 0; w < 4; ++w)
            v[w] = (tid >= off) ? sb[w][tid - off] : 0u;
        __syncthreads();
#pragma unroll
        for (int w = 0; w < 4; ++w) sb[w][tid] += v[w];
        __syncthreads();
    }

    // exclusive prefix counts per expert (inclusive - local)
    unsigned run[NUM_EXPERTS];
#pragma unroll
    for (int e = 0; e < NUM_EXPERTS; ++e)
        run[e] = ((sb[e >> 1][tid] - lc[e >> 1]) >> ((e & 1) * 16)) & 0xFFFFu;

#pragma unroll
    for (int j = 0; j < 8; ++j) {
        const int e = idx[j];
        run[e] += 1u;  // inclusive token_priority for this token's expert
        const float keep = (run[e] <= CAPACITY) ? 1.0f : 0.0f;
        float vv[NUM_EXPERTS];
#pragma unroll
        for (int k = 0; k < NUM_EXPERTS; ++k)
            vv[k] = (k == e) ? keep : 0.0f;
        float4* op = (float4*)(out_expert + (size_t)(tok0 + j) * NUM_EXPERTS);
        op[0] = make_float4(vv[0], vv[1], vv[2], vv[3]);
        op[1] = make_float4(vv[4], vv[5], vv[6], vv[7]);
    }
}

extern "C" void kernel_launch(void* const* d_in, const int* in_sizes, int n_in,
                              void* d_out, int out_size, void* d_ws, size_t ws_size,
                              hipStream_t stream) {
    const float* hs = (const float*)d_in[0];
    const float* W  = (const float*)d_in[1];
    const float* b  = (const float*)d_in[2];

    float* out        = (float*)d_out;
    float* out_expert = out;                                      // [G,T,E] one-hot (as float)
    float* out_pmax   = out + (size_t)NTOKENS * NUM_EXPERTS;      // [G,T,1]
    float* out_logits = out_pmax + NTOKENS;                       // [G,T,E]
    int*   ws_idx     = (int*)d_ws;                               // [G*T] argmax expert ids

    router_logits_kernel<<<NTOKENS / 64, 1024, 0, stream>>>(hs, W, b,
                                                            out_logits, out_pmax, ws_idx);
    router_scan_kernel<<<NGROUP, 256, 0, stream>>>(ws_idx, out_expert);
}